// Round 1
// baseline (631.204 us; speedup 1.0000x reference)
//
#include <hip/hip_runtime.h>

// SigmoidLoss: loss_ij = t_ij * log(clip(sigmoid(x_ij), eps, 1-eps));
// per row: max over positive labels, negate, weight; then mean over rows.
// log∘clip∘sigmoid is monotone => masked max over x commutes with the
// transform: find max x over positives, transform once per row.
// Pure streaming masked-max reduction => memory-bound (655 MB, one pass).
//
// R6: the timed region contains ~394us of harness poison fills (2x 1.31GB,
// seen in rocprof top-5); row_loss was ~165us (3.9 TB/s) — below the 6.3TB/s
// streaming ceiling. Restructure for guaranteed memory-level parallelism:
//  - one row per wave (4096 blocks): halves live state vs 2-row unroll
//  - explicit 2-deep double-buffered pipeline: 10 NT loads per buffer,
//    always 10-20 loads in flight across every consume phase (the old code
//    relied on the compiler hoisting the next burst past a full consume)
//  - 4 independent running-max chains (per vec4 lane) instead of one
//    40-deep serial fmax chain per group
//  - tail chunk (chunk 19, lanes<34) peeled out of the hot path
//  - __launch_bounds__(256,4): cap VGPR at 128 => 4 waves/SIMD resident

#define NROWS 16384
#define NCOLS 5000
#define NVEC  (NCOLS / 4)   // 1250 vec4 per row = 19*64 + 34
#define EPSF  1e-6f
#define NEGF  -3.0e38f

typedef float fvec4 __attribute__((ext_vector_type(4)));
typedef int   ivec4 __attribute__((ext_vector_type(4)));

__device__ __forceinline__ void load5(const fvec4* __restrict__ x4,
                                      const ivec4* __restrict__ t4,
                                      int cbase, int lane,
                                      fvec4 (&xv)[5], ivec4 (&tv)[5])
{
    #pragma unroll
    for (int k = 0; k < 5; ++k) {
        const int idx = (cbase + k) * 64 + lane;   // provably < 1250 for cbase<=14
        xv[k] = __builtin_nontemporal_load(x4 + idx);
        tv[k] = __builtin_nontemporal_load(t4 + idx);
    }
}

__device__ __forceinline__ void load5_tail(const fvec4* __restrict__ x4,
                                           const ivec4* __restrict__ t4,
                                           int lane,
                                           fvec4 (&xv)[5], ivec4 (&tv)[5])
{
    #pragma unroll
    for (int k = 0; k < 4; ++k) {                  // chunks 15..18, full
        const int idx = (15 + k) * 64 + lane;
        xv[k] = __builtin_nontemporal_load(x4 + idx);
        tv[k] = __builtin_nontemporal_load(t4 + idx);
    }
    const int idx = 19 * 64 + lane;                // chunk 19: lanes 0..33 only
    if (lane < 34) {
        xv[4] = __builtin_nontemporal_load(x4 + idx);
        tv[4] = __builtin_nontemporal_load(t4 + idx);
    } else {
        xv[4] = (fvec4)0.0f;
        tv[4] = (ivec4)0;                          // t==0 => contributes NEGF
    }
}

__device__ __forceinline__ void consume5(const fvec4 (&xv)[5], const ivec4 (&tv)[5],
                                         float& m0, float& m1, float& m2, float& m3)
{
    #pragma unroll
    for (int k = 0; k < 5; ++k) {
        m0 = fmaxf(m0, (tv[k][0] > 0) ? xv[k][0] : NEGF);
        m1 = fmaxf(m1, (tv[k][1] > 0) ? xv[k][1] : NEGF);
        m2 = fmaxf(m2, (tv[k][2] > 0) ? xv[k][2] : NEGF);
        m3 = fmaxf(m3, (tv[k][3] > 0) ? xv[k][3] : NEGF);
    }
}

__global__ __launch_bounds__(256, 4) void row_loss_kernel(
    const float* __restrict__ inp,
    const int*   __restrict__ tgt,
    const float* __restrict__ w,
    float*       __restrict__ row_loss)
{
    const int lane = threadIdx.x & 63;
    const int wid  = threadIdx.x >> 6;
    const int row  = blockIdx.x * 4 + wid;          // [0, 16384), exact cover

    const fvec4* __restrict__ x4 = (const fvec4*)(inp + (size_t)row * NCOLS);
    const ivec4* __restrict__ t4 = (const ivec4*)(tgt + (size_t)row * NCOLS);

    fvec4 xa[5], xb[5];
    ivec4 ta[5], tb[5];
    float m0 = NEGF, m1 = NEGF, m2 = NEGF, m3 = NEGF;

    // software pipeline: >=10 NT loads in flight through every consume
    load5(x4, t4, 0, lane, xa, ta);     // A <- chunks 0..4
    load5(x4, t4, 5, lane, xb, tb);     // B <- chunks 5..9   (20 in flight)
    consume5(xa, ta, m0, m1, m2, m3);   // waits A; B in flight
    load5(x4, t4, 10, lane, xa, ta);    // A <- chunks 10..14 (20 in flight)
    consume5(xb, tb, m0, m1, m2, m3);   // waits B; A in flight
    load5_tail(x4, t4, lane, xb, tb);   // B <- chunks 15..19 (masked tail)
    consume5(xa, ta, m0, m1, m2, m3);   // waits A; B in flight
    consume5(xb, tb, m0, m1, m2, m3);   // drain

    float m = fmaxf(fmaxf(m0, m1), fmaxf(m2, m3));

    // wave (64-lane) max reduction — register-only, no LDS, no barrier
    #pragma unroll
    for (int off = 32; off > 0; off >>= 1)
        m = fmaxf(m, __shfl_xor(m, off, 64));

    if (lane == 0) {
        float loss = 0.0f;
        if (m > -1.0e38f) {  // row has at least one positive
            float p = 1.0f / (1.0f + __expf(-m));
            p = fminf(fmaxf(p, EPSF), 1.0f - EPSF);
            loss = -logf(p) * w[row];
        }
        row_loss[row] = loss;  // every row written => no ws pre-zero needed
    }
}

__global__ __launch_bounds__(1024) void reduce_mean_kernel(
    const float* __restrict__ row_loss,
    float*       __restrict__ out)
{
    // 16384 floats = 4096 float4; 1024 threads x FOUR float4 each.
    const fvec4* __restrict__ rl4 = (const fvec4*)row_loss;
    float s = 0.0f;
    #pragma unroll
    for (int j = 0; j < 4; ++j) {
        fvec4 v = rl4[threadIdx.x + j * 1024];
        s += (v[0] + v[1]) + (v[2] + v[3]);
    }

    #pragma unroll
    for (int off = 32; off > 0; off >>= 1)
        s += __shfl_xor(s, off, 64);

    __shared__ float ssum[16];
    const int lane = threadIdx.x & 63;
    const int wid  = threadIdx.x >> 6;
    if (lane == 0) ssum[wid] = s;
    __syncthreads();

    if (threadIdx.x == 0) {
        float tot = 0.0f;
        #pragma unroll
        for (int i = 0; i < 16; ++i) tot += ssum[i];
        out[0] = tot / (float)NROWS;
    }
}

extern "C" void kernel_launch(void* const* d_in, const int* in_sizes, int n_in,
                              void* d_out, int out_size, void* d_ws, size_t ws_size,
                              hipStream_t stream) {
    const float* inp = (const float*)d_in[0];
    const int*   tgt = (const int*)d_in[1];
    const float* w   = (const float*)d_in[2];
    float* row_loss  = (float*)d_ws;          // 16384 floats = 64 KB scratch
    float* out       = (float*)d_out;

    row_loss_kernel<<<4096, 256, 0, stream>>>(inp, tgt, w, row_loss);
    reduce_mean_kernel<<<1, 1024, 0, stream>>>(row_loss, out);
}

// Round 2
// 573.385 us; speedup vs baseline: 1.1008x; 1.1008x over previous
//
#include <hip/hip_runtime.h>

// SigmoidLoss: loss_ij = t_ij * log(clip(sigmoid(x_ij), eps, 1-eps));
// per row: max over positive labels, negate, weight; then mean over rows.
// log∘clip∘sigmoid is monotone => masked max over x commutes with the
// transform: find max x over positives, transform once per row.
// Pure streaming masked-max reduction => memory-bound (655 MB, one pass).
//
// R7: R6 (explicit 2x10-load dbuf + launch_bounds(256,4)) REGRESSED ~50us.
// Post-mortem: 80 data VGPRs + addressing under a 128-VGPR cap => spill to
// scratch (~84MB extra traffic). gfx950 occupancy steps at VGPR {64,128,256}
// => {8,4,2} waves/SIMD (m69); R5 sat in the 65-128 band (4 waves/SIMD).
// For a pure stream, TLP is the cheap axis: fit under 64 VGPR => 8 waves/SIMD,
// 32 waves/CU x 8 loads in flight = 256 outstanding/CU, no spill risk.
//  - one row per wave, 5 groups of 4 vec4-chunks (8 NT loads per burst)
//  - #pragma unroll 1 on the group loop: one 32-VGPR buffer, reused
//  - pointer-bump addressing: +4096B/group, in-group immediates 0..3072
//  - tail group peeled (chunk 19 valid for lanes<34 only)
//  - __launch_bounds__(256, 8): request 8 waves/SIMD (VGPR cap 64)

#define NROWS 16384
#define NCOLS 5000
#define NVEC  (NCOLS / 4)   // 1250 vec4 per row = 19*64 + 34
#define EPSF  1e-6f
#define NEGF  -3.0e38f

typedef float fvec4 __attribute__((ext_vector_type(4)));
typedef int   ivec4 __attribute__((ext_vector_type(4)));

__global__ __launch_bounds__(256, 8) void row_loss_kernel(
    const float* __restrict__ inp,
    const int*   __restrict__ tgt,
    const float* __restrict__ w,
    float*       __restrict__ row_loss)
{
    const int lane = threadIdx.x & 63;
    const int wid  = threadIdx.x >> 6;
    const int row  = blockIdx.x * 4 + wid;          // [0, 16384), exact cover

    // per-lane byte pointers; chunk c lives at c*1024 + lane*16
    const char* __restrict__ xb = (const char*)(inp + (size_t)row * NCOLS) + lane * 16;
    const char* __restrict__ tb = (const char*)(tgt + (size_t)row * NCOLS) + lane * 16;

    float m0 = NEGF, m1 = NEGF, m2 = NEGF, m3 = NEGF;

    // chunks 0..15: 4 groups x 4 chunks. Single reused 32-VGPR buffer.
    #pragma unroll 1
    for (int g = 0; g < 4; ++g) {
        fvec4 xv[4];
        ivec4 tv[4];
        #pragma unroll
        for (int k = 0; k < 4; ++k)
            xv[k] = __builtin_nontemporal_load((const fvec4*)(xb + k * 1024));
        #pragma unroll
        for (int k = 0; k < 4; ++k)
            tv[k] = __builtin_nontemporal_load((const ivec4*)(tb + k * 1024));
        #pragma unroll
        for (int k = 0; k < 4; ++k) {
            m0 = fmaxf(m0, (tv[k][0] > 0) ? xv[k][0] : NEGF);
            m1 = fmaxf(m1, (tv[k][1] > 0) ? xv[k][1] : NEGF);
            m2 = fmaxf(m2, (tv[k][2] > 0) ? xv[k][2] : NEGF);
            m3 = fmaxf(m3, (tv[k][3] > 0) ? xv[k][3] : NEGF);
        }
        xb += 4096;
        tb += 4096;
    }

    // tail: chunks 16..18 full, chunk 19 only lanes < 34 (1216+lane < 1250)
    {
        fvec4 xv[4];
        ivec4 tv[4];
        #pragma unroll
        for (int k = 0; k < 3; ++k)
            xv[k] = __builtin_nontemporal_load((const fvec4*)(xb + k * 1024));
        #pragma unroll
        for (int k = 0; k < 3; ++k)
            tv[k] = __builtin_nontemporal_load((const ivec4*)(tb + k * 1024));
        if (lane < 34) {
            xv[3] = __builtin_nontemporal_load((const fvec4*)(xb + 3 * 1024));
            tv[3] = __builtin_nontemporal_load((const ivec4*)(tb + 3 * 1024));
        } else {
            xv[3] = (fvec4)0.0f;
            tv[3] = (ivec4)0;                      // t==0 => contributes NEGF
        }
        #pragma unroll
        for (int k = 0; k < 4; ++k) {
            m0 = fmaxf(m0, (tv[k][0] > 0) ? xv[k][0] : NEGF);
            m1 = fmaxf(m1, (tv[k][1] > 0) ? xv[k][1] : NEGF);
            m2 = fmaxf(m2, (tv[k][2] > 0) ? xv[k][2] : NEGF);
            m3 = fmaxf(m3, (tv[k][3] > 0) ? xv[k][3] : NEGF);
        }
    }

    float m = fmaxf(fmaxf(m0, m1), fmaxf(m2, m3));

    // wave (64-lane) max reduction — register-only, no LDS, no barrier
    #pragma unroll
    for (int off = 32; off > 0; off >>= 1)
        m = fmaxf(m, __shfl_xor(m, off, 64));

    if (lane == 0) {
        float loss = 0.0f;
        if (m > -1.0e38f) {  // row has at least one positive
            float p = 1.0f / (1.0f + __expf(-m));
            p = fminf(fmaxf(p, EPSF), 1.0f - EPSF);
            loss = -logf(p) * w[row];
        }
        row_loss[row] = loss;  // every row written => no ws pre-zero needed
    }
}

__global__ __launch_bounds__(1024) void reduce_mean_kernel(
    const float* __restrict__ row_loss,
    float*       __restrict__ out)
{
    // 16384 floats = 4096 float4; 1024 threads x FOUR float4 each.
    const fvec4* __restrict__ rl4 = (const fvec4*)row_loss;
    float s = 0.0f;
    #pragma unroll
    for (int j = 0; j < 4; ++j) {
        fvec4 v = rl4[threadIdx.x + j * 1024];
        s += (v[0] + v[1]) + (v[2] + v[3]);
    }

    #pragma unroll
    for (int off = 32; off > 0; off >>= 1)
        s += __shfl_xor(s, off, 64);

    __shared__ float ssum[16];
    const int lane = threadIdx.x & 63;
    const int wid  = threadIdx.x >> 6;
    if (lane == 0) ssum[wid] = s;
    __syncthreads();

    if (threadIdx.x == 0) {
        float tot = 0.0f;
        #pragma unroll
        for (int i = 0; i < 16; ++i) tot += ssum[i];
        out[0] = tot / (float)NROWS;
    }
}

extern "C" void kernel_launch(void* const* d_in, const int* in_sizes, int n_in,
                              void* d_out, int out_size, void* d_ws, size_t ws_size,
                              hipStream_t stream) {
    const float* inp = (const float*)d_in[0];
    const int*   tgt = (const int*)d_in[1];
    const float* w   = (const float*)d_in[2];
    float* row_loss  = (float*)d_ws;          // 16384 floats = 64 KB scratch
    float* out       = (float*)d_out;

    row_loss_kernel<<<4096, 256, 0, stream>>>(inp, tgt, w, row_loss);
    reduce_mean_kernel<<<1, 1024, 0, stream>>>(row_loss, out);
}